// Round 40
// baseline (10.501 us; speedup 1.0000x reference)
//
#include <hip/hip_runtime.h>
#include <math.h>

// Quanvolution 3x3, 9-qubit circuit, exact closed form.
//
// RY(pi*p_q) then RY(theta_q) on qubit q compose to RY(alpha_q),
// alpha_q = pi*p_q + theta_q, giving a product state with
// <Z_q> = cos(alpha_q), <X_q> = sin(alpha_q).
// Heisenberg evolution of the observable Z_0 backwards through the rest:
//   - final-layer RYs on qubits 1..6 commute with Z_0 (dead params)
//   - RY(beta=theta[9]) on q0: Z_0 -> cos(beta) Z_0 - sin(beta) X_0
//   - CNOT ring C(0,1)..C(8,0): Z_0 -> Z_1...Z_8 ; X_0 -> X_0 X_1
// =>  out = cos(beta) * prod_{q=1..8} cos(alpha_q)
//         - sin(beta) * sin(alpha_0) * sin(alpha_1)
//
// R38: passed at 9.83 us, absmax 2.4e-4 (256-thr blocks, sincosf).
// R39/R40 probe: __sincosf (fast trig) + block=64 (588 blocks, more CU
// spread), math identical. If dur_us unchanged -> launch-floor confirmed.

#define BB 16
#define HH 14
#define WW 14
#define CC 3
#define KS 4

__global__ __launch_bounds__(64) void quanv_closed_form(
    const float* __restrict__ x,    // [B,H,W,C]
    const float* __restrict__ qp,   // [KS,C,16]
    float* __restrict__ out)        // [B,H,W,KS*C]
{
    const int total = BB * HH * WW * KS * CC;
    int t = blockIdx.x * blockDim.x + threadIdx.x;
    if (t >= total) return;

    int kc = t % (KS * CC);
    int w  = (t / (KS * CC)) % WW;
    int h  = (t / (KS * CC * WW)) % HH;
    int b  =  t / (KS * CC * WW * HH);
    int k  = kc / CC;
    int c  = kc % CC;

    const float* th = qp + (k * CC + c) * 16;
    const float PI = 3.14159265358979323846f;

    // gather the 9 SAME-padded patch values
    float p[9];
    {
        int q = 0;
        for (int i = -1; i <= 1; ++i) {
            int hh = h + i;
            bool hin = (hh >= 0) & (hh < HH);
            const float* row = x + ((b * HH + hh) * WW) * CC + c;
            for (int j = -1; j <= 1; ++j, ++q) {
                int ww = w + j;
                p[q] = (hin & (ww >= 0) & (ww < WW)) ? row[ww * CC] : 0.0f;
            }
        }
    }

    float prodc = 1.0f, s0 = 0.0f, s1 = 0.0f;
#pragma unroll
    for (int q = 0; q < 9; ++q) {
        float sa, ca;
        __sincosf(fmaf(PI, p[q], th[q]), &sa, &ca);
        if (q == 0) s0 = sa; else prodc *= ca;
        if (q == 1) s1 = sa;
    }

    float sb, cb;
    __sincosf(th[9], &sb, &cb);

    out[t] = cb * prodc - sb * s0 * s1;
}

extern "C" void kernel_launch(void* const* d_in, const int* in_sizes, int n_in,
                              void* d_out, int out_size, void* d_ws, size_t ws_size,
                              hipStream_t stream) {
    const float* x  = (const float*)d_in[0];   // 16*14*14*3
    const float* qp = (const float*)d_in[1];   // 4*3*16
    float* out = (float*)d_out;                // 16*14*14*12

    const int total = BB * HH * WW * KS * CC;  // 37632
    quanv_closed_form<<<(total + 63) / 64, 64, 0, stream>>>(x, qp, out);
}

// Round 41
// 9.715 us; speedup vs baseline: 1.0809x; 1.0809x over previous
//
#include <hip/hip_runtime.h>
#include <math.h>

// Quanvolution 3x3, 9-qubit circuit, exact closed form.
//
// RY(pi*p_q) then RY(theta_q) on qubit q compose to RY(alpha_q),
// alpha_q = pi*p_q + theta_q, giving a product state with
// <Z_q> = cos(alpha_q), <X_q> = sin(alpha_q).
// Heisenberg evolution of the observable Z_0 backwards through the rest:
//   - final-layer RYs on qubits 1..6 commute with Z_0 (dead params)
//   - RY(beta=theta[9]) on q0: Z_0 -> cos(beta) Z_0 - sin(beta) X_0
//   - CNOT ring C(0,1)..C(8,0): Z_0 -> Z_1...Z_8 ; X_0 -> X_0 X_1
// =>  out = cos(beta) * prod_{q=1..8} cos(alpha_q)
//         - sin(beta) * sin(alpha_0) * sin(alpha_1)
//
// Measured: R38 (256-thr, sincosf)  = 9.83 us, absmax 2.44e-4
//           R40 (64-thr, __sincosf) = 10.50 us, absmax 2.44e-4
// -> launch-overhead-bound (~10 us harness floor); kernel internals are
//    irrelevant to dur_us. absmax identical across trig variants (error is
//    f32 closed-form vs statevector accumulation, not trig).
// R41: revert to the faster-measured 256-thr launch config; keep __sincosf.

#define BB 16
#define HH 14
#define WW 14
#define CC 3
#define KS 4

__global__ __launch_bounds__(256) void quanv_closed_form(
    const float* __restrict__ x,    // [B,H,W,C]
    const float* __restrict__ qp,   // [KS,C,16]
    float* __restrict__ out)        // [B,H,W,KS*C]
{
    const int total = BB * HH * WW * KS * CC;
    int t = blockIdx.x * blockDim.x + threadIdx.x;
    if (t >= total) return;

    int kc = t % (KS * CC);
    int w  = (t / (KS * CC)) % WW;
    int h  = (t / (KS * CC * WW)) % HH;
    int b  =  t / (KS * CC * WW * HH);
    int k  = kc / CC;
    int c  = kc % CC;

    const float* th = qp + (k * CC + c) * 16;
    const float PI = 3.14159265358979323846f;

    // gather the 9 SAME-padded patch values
    float p[9];
    {
        int q = 0;
        for (int i = -1; i <= 1; ++i) {
            int hh = h + i;
            bool hin = (hh >= 0) & (hh < HH);
            const float* row = x + ((b * HH + hh) * WW) * CC + c;
            for (int j = -1; j <= 1; ++j, ++q) {
                int ww = w + j;
                p[q] = (hin & (ww >= 0) & (ww < WW)) ? row[ww * CC] : 0.0f;
            }
        }
    }

    float prodc = 1.0f, s0 = 0.0f, s1 = 0.0f;
#pragma unroll
    for (int q = 0; q < 9; ++q) {
        float sa, ca;
        __sincosf(fmaf(PI, p[q], th[q]), &sa, &ca);
        if (q == 0) s0 = sa; else prodc *= ca;
        if (q == 1) s1 = sa;
    }

    float sb, cb;
    __sincosf(th[9], &sb, &cb);

    out[t] = cb * prodc - sb * s0 * s1;
}

extern "C" void kernel_launch(void* const* d_in, const int* in_sizes, int n_in,
                              void* d_out, int out_size, void* d_ws, size_t ws_size,
                              hipStream_t stream) {
    const float* x  = (const float*)d_in[0];   // 16*14*14*3
    const float* qp = (const float*)d_in[1];   // 4*3*16
    float* out = (float*)d_out;                // 16*14*14*12

    const int total = BB * HH * WW * KS * CC;  // 37632
    quanv_closed_form<<<(total + 255) / 256, 256, 0, stream>>>(x, qp, out);
}